// Round 2
// baseline (373.567 us; speedup 1.0000x reference)
//
#include <hip/hip_runtime.h>

#define T_LEN   65536
#define BATCH   256
#define P       64
#define K1_LEN  8192
#define DBLK    256

typedef float f4 __attribute__((ext_vector_type(4)));

// ---------------------------------------------------------------------------
// means[t] = bias * R[t] where R is the STEP RESPONSE of the AR(64) filter:
//   R[t] = sum_k params[k]*R[t-1-k] + 1,  R[t<0] = 0
// Extension identity:
//   R[L+tau] = R[tau] + sum_{i=0}^{64} V[i]*R[tau-i]
//   V[i] = W[i]-W[i-1],  W[j] = sum_{m=0}^{63-j} params[m+j]*R[L-1-m]
// ---------------------------------------------------------------------------

// Phase 1a: serial 64 steps (transposed-form IIR on wave 0) + in-LDS doubling
// 64 -> 8192, single workgroup. Inner FIR uses a rolling 2xfloat4 register
// window over ds_read_b128 (lane stride 16B = conflict-free) — R1 fix for the
// VGPR-spill that made the w[68] version 65 us.
__global__ __launch_bounds__(1024) void ar_k1(const float* __restrict__ params,
                                              float* __restrict__ R) {
    __shared__ __align__(16) float Rl[K1_LEN];
    __shared__ float p[P];
    __shared__ __align__(16) float Vs[68];
    const int tid = threadIdx.x;
    if (tid < P) p[tid] = params[tid];
    __syncthreads();

    // Serial stage: lane k holds transposed-form state z_{k+1}.
    if (tid < 64) {
        float z = 0.f;
        const float pk = p[tid];
        for (int t = 0; t < 64; ++t) {
            float y  = __shfl(z, 0) + 1.0f;   // R[t]
            float zn = __shfl_down(z, 1);
            if (tid == 63) zn = 0.f;
            z = fmaf(pk, y, zn);
            if (tid == 0) Rl[t] = y;
        }
    }
    __syncthreads();

    for (int L = 64; L < K1_LEN; L <<= 1) {
        if (tid <= P) {
            const int j = tid;
            float W0 = 0.f, W1 = 0.f;
            if (j <= P - 1)
                for (int m = 0; m <= P - 1 - j; ++m) W0 = fmaf(p[m + j], Rl[L - 1 - m], W0);
            if (j >= 1)
                for (int m = 0; m <= P - j; ++m) W1 = fmaf(p[m + j - 1], Rl[L - 1 - m], W1);
            Vs[j] = W0 - W1;
        }
        __syncthreads();
        // boundary outputs tau in [0,64): R[tau-i]=0 for i>tau
        if (tid < 64) {
            const int tau = tid;
            float acc = Rl[tau];
            for (int i = 0; i <= tau; ++i) acc = fmaf(Vs[i], Rl[tau - i], acc);
            Rl[L + tau] = acc;
        }
        // blocked outputs tau in [64,L): 4 per quad, rolling float4 window.
        // Quad q covers outputs L+64+4q..+3; window floats Rl[4q .. 4q+67].
        {
            const f4* __restrict__ Rl4 = reinterpret_cast<const f4*>(Rl);
            f4* __restrict__ Rl4w = reinterpret_cast<f4*>(Rl);
            const f4* __restrict__ V4 = reinterpret_cast<const f4*>(Vs);
            const int nq = (L - 64) >> 2;
            for (int q = tid; q < nq; q += 1024) {
                f4 hi = Rl4[q + 16];          // floats 64..67 (= R[tau_j] term)
                f4 lo = Rl4[q + 15];          // floats 60..63
                float a0 = hi.x, a1 = hi.y, a2 = hi.z, a3 = hi.w;
                #pragma unroll
                for (int g = 0; g < 16; ++g) {   // i = 4g..4g+3
                    const f4 v = V4[g];
                    a0 = fmaf(v.x, hi.x, a0); a1 = fmaf(v.x, hi.y, a1);
                    a2 = fmaf(v.x, hi.z, a2); a3 = fmaf(v.x, hi.w, a3);
                    a0 = fmaf(v.y, lo.w, a0); a1 = fmaf(v.y, hi.x, a1);
                    a2 = fmaf(v.y, hi.y, a2); a3 = fmaf(v.y, hi.z, a3);
                    a0 = fmaf(v.z, lo.z, a0); a1 = fmaf(v.z, lo.w, a1);
                    a2 = fmaf(v.z, hi.x, a2); a3 = fmaf(v.z, hi.y, a3);
                    a0 = fmaf(v.w, lo.y, a0); a1 = fmaf(v.w, lo.z, a1);
                    a2 = fmaf(v.w, lo.w, a2); a3 = fmaf(v.w, hi.x, a3);
                    hi = lo;
                    if (g < 15) lo = Rl4[q + 14 - g];
                }
                const float v64 = Vs[64];     // i = 64 -> floats 0..3 (= hi now)
                a0 = fmaf(v64, hi.x, a0); a1 = fmaf(v64, hi.y, a1);
                a2 = fmaf(v64, hi.z, a2); a3 = fmaf(v64, hi.w, a3);
                f4 o; o.x = a0; o.y = a1; o.z = a2; o.w = a3;
                Rl4w[((L + 64) >> 2) + q] = o;
            }
        }
        __syncthreads();
    }

    for (int j = tid; j < K1_LEN / 4; j += 1024)
        reinterpret_cast<f4*>(R)[j] = reinterpret_cast<const f4*>(Rl)[j];
}

// Phase 1b: grid-wide doubling R[0..L) -> R[L..2L).
__global__ __launch_bounds__(DBLK) void ar_double(const float* __restrict__ params,
                                                  float* __restrict__ R, const int L) {
    __shared__ float p[P];
    __shared__ float V[P + 1];
    __shared__ float win[DBLK + P];
    const int tid = threadIdx.x;
    const int B0  = blockIdx.x * DBLK;
    if (tid < P) p[tid] = params[tid];
    __syncthreads();
    if (tid <= P) {
        const int j = tid;
        float W0 = 0.f, W1 = 0.f;
        if (j <= P - 1)
            for (int m = 0; m <= P - 1 - j; ++m) W0 = fmaf(p[m + j], R[L - 1 - m], W0);
        if (j >= 1)
            for (int m = 0; m <= P - j; ++m) W1 = fmaf(p[m + j - 1], R[L - 1 - m], W1);
        V[j] = W0 - W1;
    }
    for (int j = tid; j < DBLK + P; j += DBLK) {
        const int g = B0 - P + j;
        win[j] = (g >= 0) ? R[g] : 0.f;   // zero-pad only affects block 0
    }
    __syncthreads();
    float acc = win[P + tid];
    #pragma unroll
    for (int i = 0; i <= P; ++i) acc = fmaf(V[i], win[P + tid - i], acc);
    R[L + B0 + tid] = acc;
}

// Phase 2: out[b,t] = bias*R[t] + 0.3*noise[b,t]  (memory-bound, float4,
// nontemporal on the 128 MB streaming traffic so R stays L2-resident)
__global__ __launch_bounds__(256) void ar_out(const float* __restrict__ R,
                                              const float* __restrict__ bias,
                                              const float* __restrict__ noise,
                                              float* __restrict__ out) {
    const int i4 = blockIdx.x * 256 + threadIdx.x;       // float4 index
    const float b = bias[0];
    const int t4 = i4 & (T_LEN / 4 - 1);                 // T divisible by 4
    const f4 r4 = reinterpret_cast<const f4*>(R)[t4];
    const f4 n4 = __builtin_nontemporal_load(reinterpret_cast<const f4*>(noise) + i4);
    f4 o;
    o.x = fmaf(0.3f, n4.x, b * r4.x);
    o.y = fmaf(0.3f, n4.y, b * r4.y);
    o.z = fmaf(0.3f, n4.z, b * r4.z);
    o.w = fmaf(0.3f, n4.w, b * r4.w);
    __builtin_nontemporal_store(o, reinterpret_cast<f4*>(out) + i4);
}

extern "C" void kernel_launch(void* const* d_in, const int* in_sizes, int n_in,
                              void* d_out, int out_size, void* d_ws, size_t ws_size,
                              hipStream_t stream) {
    const float* params = (const float*)d_in[0];
    const float* bias   = (const float*)d_in[1];
    const float* noise  = (const float*)d_in[2];
    float* out = (float*)d_out;
    float* R   = (float*)d_ws;              // 65536 floats = 256 KiB scratch

    hipLaunchKernelGGL(ar_k1, dim3(1), dim3(1024), 0, stream, params, R);
    for (int L = K1_LEN; L < T_LEN; L <<= 1)
        hipLaunchKernelGGL(ar_double, dim3(L / DBLK), dim3(DBLK), 0, stream,
                           params, R, L);
    hipLaunchKernelGGL(ar_out, dim3((BATCH * (T_LEN / 4)) / 256), dim3(256),
                       0, stream, R, bias, noise, out);
}

// Round 3
// 247.648 us; speedup vs baseline: 1.5085x; 1.5085x over previous
//
#include <hip/hip_runtime.h>

#define T_LEN   65536
#define BATCH   256
#define P       64
#define K1_LEN  8192
#define K1_THREADS 512
#define DBLK    256

typedef float f4 __attribute__((ext_vector_type(4)));

// ---------------------------------------------------------------------------
// means[t] = bias * R[t] where R is the STEP RESPONSE of the AR(64) filter:
//   R[t] = sum_k params[k]*R[t-1-k] + 1,  R[t<0] = 0
// Extension identity:
//   R[L+tau] = R[tau] + sum_{i=0}^{64} V[i]*R[tau-i]
//   V[i] = W[i]-W[i-1],  W[j] = sum_{m=0}^{63-j} params[m+j]*R[L-1-m]
// ---------------------------------------------------------------------------

// Phase 1a: serial 64 steps + in-LDS doubling 64 -> 8192, single workgroup.
// R2: block=512 + __launch_bounds__(512,2) gives a 256-VGPR budget so the
// 68-float register window (17 x ds_read_b128, conflict-free) fits WITHOUT
// spilling — R1's 1024-thread/64-VGPR config spilled it to scratch (431 KB
// FETCH / 911 KB WRITE per dispatch, 244 us).
__global__ __launch_bounds__(K1_THREADS, 2) void ar_k1(const float* __restrict__ params,
                                                       float* __restrict__ R) {
    __shared__ __align__(16) float Rl[K1_LEN];
    __shared__ float p[P];
    __shared__ __align__(16) float Vs[68];
    const int tid = threadIdx.x;
    if (tid < P) p[tid] = params[tid];
    __syncthreads();

    // Serial stage: lane k holds transposed-form state z_{k+1}.
    if (tid < 64) {
        float z = 0.f;
        const float pk = p[tid];
        for (int t = 0; t < 64; ++t) {
            float y  = __shfl(z, 0) + 1.0f;   // R[t]
            float zn = __shfl_down(z, 1);
            if (tid == 63) zn = 0.f;
            z = fmaf(pk, y, zn);
            if (tid == 0) Rl[t] = y;
        }
    }
    __syncthreads();

    for (int L = 64; L < K1_LEN; L <<= 1) {
        if (tid <= P) {
            const int j = tid;
            float W0 = 0.f, W1 = 0.f;
            if (j <= P - 1)
                for (int m = 0; m <= P - 1 - j; ++m) W0 = fmaf(p[m + j], Rl[L - 1 - m], W0);
            if (j >= 1)
                for (int m = 0; m <= P - j; ++m) W1 = fmaf(p[m + j - 1], Rl[L - 1 - m], W1);
            Vs[j] = W0 - W1;
        }
        __syncthreads();
        // boundary outputs tau in [0,64): R[tau-i]=0 for i>tau
        if (tid < 64) {
            const int tau = tid;
            float acc = Rl[tau];
            for (int i = 0; i <= tau; ++i) acc = fmaf(Vs[i], Rl[tau - i], acc);
            Rl[L + tau] = acc;
        }
        // blocked outputs tau in [64,L): 4 per quad. Whole 68-float window
        // preloaded into registers (fits the 256-VGPR budget at 512 threads).
        {
            const f4* __restrict__ Rl4 = reinterpret_cast<const f4*>(Rl);
            f4* __restrict__ Rl4w = reinterpret_cast<f4*>(Rl);
            const f4* __restrict__ V4 = reinterpret_cast<const f4*>(Vs);
            const int nq = (L - 64) >> 2;
            #pragma unroll 1
            for (int q = tid; q < nq; q += K1_THREADS) {
                f4 w4[17];
                #pragma unroll
                for (int j = 0; j < 17; ++j) w4[j] = Rl4[q + j];
                float a0 = w4[16].x, a1 = w4[16].y, a2 = w4[16].z, a3 = w4[16].w;
                #pragma unroll
                for (int g = 0; g < 16; ++g) {   // i = 4g..4g+3
                    const f4 v  = V4[g];
                    const f4 hi = w4[16 - g];
                    const f4 lo = w4[15 - g];
                    a0 = fmaf(v.x, hi.x, a0); a1 = fmaf(v.x, hi.y, a1);
                    a2 = fmaf(v.x, hi.z, a2); a3 = fmaf(v.x, hi.w, a3);
                    a0 = fmaf(v.y, lo.w, a0); a1 = fmaf(v.y, hi.x, a1);
                    a2 = fmaf(v.y, hi.y, a2); a3 = fmaf(v.y, hi.z, a3);
                    a0 = fmaf(v.z, lo.z, a0); a1 = fmaf(v.z, lo.w, a1);
                    a2 = fmaf(v.z, hi.x, a2); a3 = fmaf(v.z, hi.y, a3);
                    a0 = fmaf(v.w, lo.y, a0); a1 = fmaf(v.w, lo.z, a1);
                    a2 = fmaf(v.w, lo.w, a2); a3 = fmaf(v.w, hi.x, a3);
                }
                const float v64 = Vs[64];     // i = 64 -> floats 0..3
                a0 = fmaf(v64, w4[0].x, a0); a1 = fmaf(v64, w4[0].y, a1);
                a2 = fmaf(v64, w4[0].z, a2); a3 = fmaf(v64, w4[0].w, a3);
                f4 o; o.x = a0; o.y = a1; o.z = a2; o.w = a3;
                Rl4w[((L + 64) >> 2) + q] = o;
            }
        }
        __syncthreads();
    }

    for (int j = tid; j < K1_LEN / 4; j += K1_THREADS)
        reinterpret_cast<f4*>(R)[j] = reinterpret_cast<const f4*>(Rl)[j];
}

// Phase 1b: grid-wide doubling R[0..L) -> R[L..2L). R2: tail staged through
// LDS so the W sums chain on ~4-cyc FMA latency, not ~200-cyc L2 loads.
__global__ __launch_bounds__(DBLK) void ar_double(const float* __restrict__ params,
                                                  float* __restrict__ R, const int L) {
    __shared__ float p[P];
    __shared__ float tail[P];        // tail[m] = R[L-1-m]
    __shared__ float V[P + 1];
    __shared__ float win[DBLK + P];
    const int tid = threadIdx.x;
    const int B0  = blockIdx.x * DBLK;
    if (tid < P) {
        p[tid] = params[tid];
        tail[tid] = R[L - 1 - tid];
    }
    for (int j = tid; j < DBLK + P; j += DBLK) {
        const int g = B0 - P + j;
        win[j] = (g >= 0) ? R[g] : 0.f;   // zero-pad only affects block 0
    }
    __syncthreads();
    if (tid <= P) {
        const int j = tid;
        float W0 = 0.f, W1 = 0.f;
        if (j <= P - 1)
            for (int m = 0; m <= P - 1 - j; ++m) W0 = fmaf(p[m + j], tail[m], W0);
        if (j >= 1)
            for (int m = 0; m <= P - j; ++m) W1 = fmaf(p[m + j - 1], tail[m], W1);
        V[j] = W0 - W1;
    }
    __syncthreads();
    float acc = win[P + tid];
    #pragma unroll
    for (int i = 0; i <= P; ++i) acc = fmaf(V[i], win[P + tid - i], acc);
    R[L + B0 + tid] = acc;
}

// Phase 2: out[b,t] = bias*R[t] + 0.3*noise[b,t]  (memory-bound, float4,
// nontemporal on the 128 MB streaming traffic so R stays L2-resident)
__global__ __launch_bounds__(256) void ar_out(const float* __restrict__ R,
                                              const float* __restrict__ bias,
                                              const float* __restrict__ noise,
                                              float* __restrict__ out) {
    const int i4 = blockIdx.x * 256 + threadIdx.x;       // float4 index
    const float b = bias[0];
    const int t4 = i4 & (T_LEN / 4 - 1);                 // T divisible by 4
    const f4 r4 = reinterpret_cast<const f4*>(R)[t4];
    const f4 n4 = __builtin_nontemporal_load(reinterpret_cast<const f4*>(noise) + i4);
    f4 o;
    o.x = fmaf(0.3f, n4.x, b * r4.x);
    o.y = fmaf(0.3f, n4.y, b * r4.y);
    o.z = fmaf(0.3f, n4.z, b * r4.z);
    o.w = fmaf(0.3f, n4.w, b * r4.w);
    __builtin_nontemporal_store(o, reinterpret_cast<f4*>(out) + i4);
}

extern "C" void kernel_launch(void* const* d_in, const int* in_sizes, int n_in,
                              void* d_out, int out_size, void* d_ws, size_t ws_size,
                              hipStream_t stream) {
    const float* params = (const float*)d_in[0];
    const float* bias   = (const float*)d_in[1];
    const float* noise  = (const float*)d_in[2];
    float* out = (float*)d_out;
    float* R   = (float*)d_ws;              // 65536 floats = 256 KiB scratch

    hipLaunchKernelGGL(ar_k1, dim3(1), dim3(K1_THREADS), 0, stream, params, R);
    for (int L = K1_LEN; L < T_LEN; L <<= 1)
        hipLaunchKernelGGL(ar_double, dim3(L / DBLK), dim3(DBLK), 0, stream,
                           params, R, L);
    hipLaunchKernelGGL(ar_out, dim3((BATCH * (T_LEN / 4)) / 256), dim3(256),
                       0, stream, R, bias, noise, out);
}